// Round 22
// baseline (118.196 us; speedup 1.0000x reference)
//
#include <hip/hip_runtime.h>
#include <hip/hip_bf16.h>

// HaloNet block attention. B=8, C=128, H=W=128, HEADS=4, D=32, BLOCK=8, HALO=3,
// WIN=14, slots padded to 14x16=224.
//
// FINAL = R15/R20 optimum (104.7 us confirmed twice) + wcvt folded into
// qkv_gemm (weights converted inline, bit-identical f2bf(w*QSCALE); saves one
// kernel launch + ws_w round trip). All other structural levers falsified:
// R16 qhv hoist (-occupancy), R18 ot-split (2x x traffic), R19 pixel-split
// (halved load amortization), R8/R9 forced prefetch (allocator/asm hazards).
//
// 2-kernel pipeline through d_ws:
//   ws_q : bf16 [b][i][j][head][64 qrow][32 d]           (block-gathered, prescaled)
//   ws_k : bf16 [b*4+head][16384 pix][32 d]              (head-major pixel-major)
//   ws_v : bf16 [b*4+head][row 128][colquad 32][d 32][4] (quad-interleaved v)
// Fallback (ws too small): round-0 fused kernel.

typedef __attribute__((ext_vector_type(8))) short bf16x8;
typedef __attribute__((ext_vector_type(4))) short bf16x4;
typedef __attribute__((ext_vector_type(4))) float f32x4;
union BF8 { bf16x8 v; unsigned u[4]; };
union BF4 { bf16x4 v; unsigned u[2]; };

#define DEVI static __device__ __forceinline__

DEVI short f2bf(float f) {
    __bf16 h = (__bf16)f;                      // fptrunc (RNE)
    union { __bf16 h; short s; } c; c.h = h; return c.s;
}
DEVI unsigned pk2(float a, float b) {
    return (unsigned)(unsigned short)f2bf(a) | ((unsigned)(unsigned short)f2bf(b) << 16);
}

#if defined(__has_builtin)
#  if __has_builtin(__builtin_amdgcn_exp2f)
#    define EXP2(x) __builtin_amdgcn_exp2f(x)
#  else
#    define EXP2(x) exp2f(x)
#  endif
#else
#  define EXP2(x) exp2f(x)
#endif

#if defined(__has_builtin)
#  if __has_builtin(__builtin_amdgcn_mfma_f32_16x16x16bf16_1k)
#    define HAVE_MFMA16_1K 1
#  endif
#endif

DEVI f32x4 mfma16(bf16x4 a, bf16x4 b, f32x4 c) {
#ifdef HAVE_MFMA16_1K
    return __builtin_amdgcn_mfma_f32_16x16x16bf16_1k(a, b, c, 0, 0, 0);
#else
    f32x4 d;
    asm("v_mfma_f32_16x16x16_bf16 %0, %1, %2, %3" : "=v"(d) : "v"(a), "v"(b), "v"(c));
    return d;
#endif
}

// q prescale: d^-0.5 * 1/ln2  (sim computed in log2 units; exp2 in softmax)
#define QSCALE (0.17677669529663687f * 1.4426950408889634f)

// ---------------- kernel 1: QKV GEMM (M=384 o, N=131072 pix, K=128) ----------------
// Weights read as fp32 and converted inline (exact wcvt semantics: rows 0..127
// scaled by QSCALE). W = 196KB -> L2-resident after the first block.
__launch_bounds__(256)
__global__ void qkv_gemm(const float* __restrict__ x, const float* __restrict__ w,
                         short* __restrict__ ws_q, short* __restrict__ ws_k,
                         short* __restrict__ ws_v) {
    const int blk = blockIdx.x;
    const int b = blk >> 6;
    const int pixbase = (blk & 63) << 8;
    const int tid = threadIdx.x, wv = tid >> 6, ln = tid & 63;
    const int lr = ln & 15, lg = ln >> 4;
    const int n0 = pixbase + wv * 64;
    const f32x4 zz = {0.f, 0.f, 0.f, 0.f};

    // B-frags: X[c][pix]; lane lr = pix col, lg*8+e = channel. As an A-frag the
    // same registers represent X^T[pix][c] (identical lane->element indexing).
    BF8 Bx[4][4];
    #pragma unroll
    for (int nt = 0; nt < 4; ++nt) {
        const int pix = n0 + nt * 16 + lr;
        #pragma unroll
        for (int ks = 0; ks < 4; ++ks) {
            const float* xp = x + (((size_t)((b << 7) + ks * 32 + lg * 8)) << 14) + pix;
            float f[8];
            #pragma unroll
            for (int e = 0; e < 8; ++e) f[e] = xp[(size_t)e << 14];
            Bx[nt][ks].u[0] = pk2(f[0], f[1]); Bx[nt][ks].u[1] = pk2(f[2], f[3]);
            Bx[nt][ks].u[2] = pk2(f[4], f[5]); Bx[nt][ks].u[3] = pk2(f[6], f[7]);
        }
    }

    for (int ot = 0; ot < 24; ++ot) {
        // inline weight convert (bit-identical to the old wcvt: f2bf(w*QSCALE)
        // for output rows < 128, i.e. ot < 8; plain f2bf otherwise)
        const float wsc = (ot < 8) ? QSCALE : 1.0f;
        bf16x8 Aw[4];
        #pragma unroll
        for (int ks = 0; ks < 4; ++ks) {
            const float* wp = w + (ot * 16 + lr) * 128 + ks * 32 + lg * 8;
            BF8 t;
            t.u[0] = pk2(wp[0] * wsc, wp[1] * wsc);
            t.u[1] = pk2(wp[2] * wsc, wp[3] * wsc);
            t.u[2] = pk2(wp[4] * wsc, wp[5] * wsc);
            t.u[3] = pk2(wp[6] * wsc, wp[7] * wsc);
            Aw[ks] = t.v;
        }

        if (ot < 16) {                       // q/k: C[o][pix], 8B packed stores
            f32x4 acc[4];
            #pragma unroll
            for (int nt = 0; nt < 4; ++nt) {
                acc[nt] = zz;
                #pragma unroll
                for (int ks = 0; ks < 4; ++ks)
                    acc[nt] = __builtin_amdgcn_mfma_f32_16x16x32_bf16(Aw[ks], Bx[nt][ks].v, acc[nt], 0, 0, 0);
            }
            if (ot < 8) {                    // q -> block-gathered [blkhead][qrow][32]
                const int head = ot >> 1, dd0 = ((ot & 1) << 4) + lg * 4;
                #pragma unroll
                for (int nt = 0; nt < 4; ++nt) {
                    const int pix = n0 + nt * 16 + lr;
                    const int gr = pix >> 7, gc = pix & 127;
                    const int ii = gr >> 3, jj = gc >> 3;
                    const int qrow = ((gr & 7) << 3) | (gc & 7);
                    size_t off = ((size_t)((((b * 16 + ii) * 16 + jj) << 2) + head) << 11) + qrow * 32 + dd0;
                    *(uint2*)&ws_q[off] = make_uint2(pk2(acc[nt][0], acc[nt][1]), pk2(acc[nt][2], acc[nt][3]));
                }
            } else {                         // k -> [bh][pix][32]
                const int head = (ot - 8) >> 1, dd0 = (((ot - 8) & 1) << 4) + lg * 4;
                const size_t kb = ((size_t)(b * 4 + head)) << 19;
                #pragma unroll
                for (int nt = 0; nt < 4; ++nt) {
                    const int pix = n0 + nt * 16 + lr;
                    *(uint2*)&ws_k[kb + pix * 32 + dd0] =
                        make_uint2(pk2(acc[nt][0], acc[nt][1]), pk2(acc[nt][2], acc[nt][3]));
                }
            }
        } else {                             // v: SWAPPED mfma -> C[pix][o] (proven R8)
            const int vch = ((ot - 16) << 4) + lr;     // o - 256 for this lane
            const int headv = vch >> 5, dv = vch & 31;
            f32x4 accT[4];
            #pragma unroll
            for (int nt = 0; nt < 4; ++nt) {
                accT[nt] = zz;
                #pragma unroll
                for (int ks = 0; ks < 4; ++ks)
                    accT[nt] = __builtin_amdgcn_mfma_f32_16x16x32_bf16(Bx[nt][ks].v, Aw[ks], accT[nt], 0, 0, 0);
            }
            #pragma unroll
            for (int nt = 0; nt < 4; ++nt) {
                const int pixq = n0 + nt * 16 + lg * 4;   // 4-aligned, quad in one row
                const int gr = pixq >> 7, gcq = (pixq & 127) >> 2;
                const size_t idx = ((((size_t)(b * 4 + headv) * 128 + gr) * 32 + gcq) * 32 + dv) * 4;
                *(uint2*)&ws_v[idx] =
                    make_uint2(pk2(accT[nt][0], accT[nt][1]), pk2(accT[nt][2], accT[nt][3]));
            }
        }
    }
}

// ---------------- kernel 2: attention; block=(b,i,j,half), wave=head, 32 qrows ----------------
template<bool EDGE>
DEVI void attn_body(int b, int i, int j, int head, int ln, int mt0,
                    const short* __restrict__ ws_q, const short* __restrict__ ws_k,
                    const short* __restrict__ ws_v,
                    const float* __restrict__ rel_h, const float* __restrict__ rel_w,
                    float* __restrict__ out) {
    const int lr = ln & 15, lg = ln >> 4;
    const f32x4 zz = {0.f, 0.f, 0.f, 0.f};
    const int bh = b * 4 + head;

    const short* qbase = ws_q + ((size_t)((((b * 16 + i) * 16 + j) << 2) + head) << 11);
    const short* kbase = ws_k + (((size_t)bh) << 19);
    const short* vbase = ws_v + (((size_t)bh) << 19);   // 128*32*32*4 = 2^19

    // q B-frags for this wave's 2 m-tiles (n = qrow = (mt0+m)*16+lr, k = d = lg*8+e)
    bf16x8 Bq[2];
    #pragma unroll
    for (int m = 0; m < 2; ++m)
        Bq[m] = *(const bf16x8*)&qbase[((mt0 + m) * 16 + lr) * 32 + lg * 8];

    // rel-pos A-frags: Ah = rel_h (m-row = wr, d 0..15), Aw (m-row = wc, d 16..31)
    BF8 Ah, Awf;
    #pragma unroll
    for (int wd = 0; wd < 4; ++wd) { Ah.u[wd] = 0u; Awf.u[wd] = 0u; }
    if (lr < 14) {
        if (lg < 2) {
            const float* rp = rel_h + lr * 16 + lg * 8;
            #pragma unroll
            for (int wd = 0; wd < 4; ++wd) Ah.u[wd] = pk2(rp[2 * wd], rp[2 * wd + 1]);
        } else {
            const float* rp = rel_w + lr * 16 + (lg - 2) * 8;
            #pragma unroll
            for (int wd = 0; wd < 4; ++wd) Awf.u[wd] = pk2(rp[2 * wd], rp[2 * wd + 1]);
        }
    }
    // qh4[m][r] = qh(qrow, wr=lg*4+r); qw4[m][r] = qw(qrow, wc=lg*4+r)
    f32x4 qh4[2], qw4[2];
    #pragma unroll
    for (int m = 0; m < 2; ++m) {
        qh4[m] = __builtin_amdgcn_mfma_f32_16x16x32_bf16(Ah.v, Bq[m], zz, 0, 0, 0);
        qw4[m] = __builtin_amdgcn_mfma_f32_16x16x32_bf16(Awf.v, Bq[m], zz, 0, 0, 0);
    }
    if (lg == 3) {     // phantom slots wc=14,15: bias -> -16384 so exp2 -> exact 0
        #pragma unroll
        for (int m = 0; m < 2; ++m) { qw4[m][2] = -16384.f; qw4[m][3] = -16384.f; }
    }

    BF4 Bones; Bones.u[0] = 0x3F803F80u; Bones.u[1] = 0x3F803F80u;

    // t-invariant edge precompute
    const int gc   = j * 8 - 3 + lr;                       // K column for this lane
    const int gcc  = EDGE ? min(max(gc, 0), 127) : gc;
    const bool gcBad = EDGE && (gc != gcc);
    // V: lane needs window cols gc0..gc0+3, gc0 = j*8-3+lg*4 (== 1 mod 4):
    // quad A = 2j+lg-1 supplies cols {1,2,3}; quad B = A+1 supplies col {0}.
    const int qAraw = 2 * j + lg - 1;
    const int qA = EDGE ? min(max(qAraw, 0), 31) : qAraw;
    const int qB = EDGE ? min(qAraw + 1, 31) : (qAraw + 1);
    const int oA0 = (qA * 32 + lr) * 4;        // quad A, d = lr
    const int oA1 = oA0 + 64;                  // quad A, d = 16+lr
    const int oB0 = (qB * 32 + lr) * 4;
    const int oB1 = oB0 + 64;
    unsigned mmc0 = 0xFFFFFFFFu, mmc1 = 0xFFFFFFFFu;
    if (EDGE) {
        const int gc0 = j * 8 - 3 + lg * 4;
        const int lo = max(0, -gc0), hi = min(3, 127 - gc0);
        const unsigned bits = (lo <= hi) ? (((0xFu >> (3 - (hi - lo))) << lo) & 0xFu) : 0u;
        mmc0 = ((bits & 1u) ? 0x0000FFFFu : 0u) | ((bits & 2u) ? 0xFFFF0000u : 0u);
        mmc1 = ((bits & 4u) ? 0x0000FFFFu : 0u) | ((bits & 8u) ? 0xFFFF0000u : 0u);
    }

    // two independent accumulator sets: stream A (t=0..6), stream B (t=7..13)
    f32x4 a0A[2] = {zz, zz}, a1A[2] = {zz, zz}, sAA[2] = {zz, zz};
    f32x4 a0B[2] = {zz, zz}, a1B[2] = {zz, zz}, sAB[2] = {zz, zz};

#define STEP(T, A0, A1, SA) { \
        const int gr_ = i * 8 - 3 + (T); \
        const bool grOK_ = !EDGE || ((unsigned)gr_ < 128u); \
        const int grc_ = EDGE ? min(max(gr_, 0), 127) : gr_; \
        BF8 Ak_; \
        Ak_.v = *(const bf16x8*)&kbase[((grc_ << 7) + gcc) * 32 + lg * 8]; \
        if (EDGE && (gcBad || !grOK_)) { Ak_.u[0] = 0; Ak_.u[1] = 0; Ak_.u[2] = 0; Ak_.u[3] = 0; } \
        const int vrow_ = grc_ << 12; \
        const uint2 aA0_ = *(const uint2*)&vbase[vrow_ + oA0]; \
        const uint2 aA1_ = *(const uint2*)&vbase[vrow_ + oA1]; \
        const unsigned bB0_ = *(const unsigned short*)&vbase[vrow_ + oB0]; \
        const unsigned bB1_ = *(const unsigned short*)&vbase[vrow_ + oB1]; \
        BF4 Bv0_, Bv1_; \
        Bv0_.u[0] = __builtin_amdgcn_alignbit(aA0_.y, aA0_.x, 16); \
        Bv0_.u[1] = __builtin_amdgcn_alignbit(bB0_, aA0_.y, 16); \
        Bv1_.u[0] = __builtin_amdgcn_alignbit(aA1_.y, aA1_.x, 16); \
        Bv1_.u[1] = __builtin_amdgcn_alignbit(bB1_, aA1_.y, 16); \
        if (EDGE) { \
            const unsigned mm0_ = grOK_ ? mmc0 : 0u; \
            const unsigned mm1_ = grOK_ ? mmc1 : 0u; \
            Bv0_.u[0] &= mm0_; Bv0_.u[1] &= mm1_; Bv1_.u[0] &= mm0_; Bv1_.u[1] &= mm1_; \
        } \
        _Pragma("unroll") \
        for (int m = 0; m < 2; ++m) { \
            const float qh_ = __shfl(qh4[m][(T) & 3], (((T) >> 2) << 4) | lr, 64); \
            f32x4 cin_; \
            _Pragma("unroll") \
            for (int r = 0; r < 4; ++r) cin_[r] = qw4[m][r] + qh_; \
            const f32x4 p_ = __builtin_amdgcn_mfma_f32_16x16x32_bf16(Ak_.v, Bq[m], cin_, 0, 0, 0); \
            BF4 Ap_; \
            Ap_.u[0] = pk2(EXP2(p_[0]), EXP2(p_[1])); \
            Ap_.u[1] = pk2(EXP2(p_[2]), EXP2(p_[3])); \
            A0[m] = mfma16(Ap_.v, Bv0_.v, A0[m]); \
            A1[m] = mfma16(Ap_.v, Bv1_.v, A1[m]); \
            SA[m] = mfma16(Ap_.v, Bones.v, SA[m]); \
        } \
    }

    #pragma unroll
    for (int t = 0; t < 7; ++t) {
        STEP(t,     a0A, a1A, sAA)
        STEP(t + 7, a0B, a1B, sAB)
    }
#undef STEP

    // epilogue: merge streams; s for qrow = (mt0+m)*16+lg*4+r is in reg r of this lane
    #pragma unroll
    for (int m = 0; m < 2; ++m) {
        f32x4 acc0, acc1;
        #pragma unroll
        for (int r = 0; r < 4; ++r) {
            const float rinv = __builtin_amdgcn_rcpf(sAA[m][r] + sAB[m][r]);
            acc0[r] = (a0A[m][r] + a0B[m][r]) * rinv;
            acc1[r] = (a1A[m][r] + a1B[m][r]) * rinv;
        }
        const int qb = (mt0 + m) * 16 + lg * 4;
        float* op = out + (((size_t)(b * 128 + head * 32)) << 14)
                        + ((i * 8 + (qb >> 3)) << 7) + j * 8 + (qb & 7);
        *(f32x4*)(op + ((size_t)lr << 14)) = acc0;
        *(f32x4*)(op + ((size_t)(16 + lr) << 14)) = acc1;
    }
}

__launch_bounds__(256, 2)
__global__ void attn4(const short* __restrict__ ws_q, const short* __restrict__ ws_k,
                      const short* __restrict__ ws_v,
                      const float* __restrict__ rel_h, const float* __restrict__ rel_w,
                      float* __restrict__ out) {
    // L2-capacity-aware XCD swizzle (R12; ~neutral vs R11 but passing/kept).
    const int bid = blockIdx.x;
    const int x = bid & 7, n = bid >> 3;
    const int g = x + ((n >> 7) << 3);
    const int l = n & 127;
    const int b = g >> 2;
    const int i = ((g & 3) << 2) | (l >> 5);
    const int j = (l >> 1) & 15;
    const int half = l & 1;
    const int head = threadIdx.x >> 6, ln = threadIdx.x & 63;
    if (i == 0 || i == 15 || j == 0 || j == 15)
        attn_body<true>(b, i, j, head, ln, half * 2, ws_q, ws_k, ws_v, rel_h, rel_w, out);
    else
        attn_body<false>(b, i, j, head, ln, half * 2, ws_q, ws_k, ws_v, rel_h, rel_w, out);
}

// ---------------- fallback: round-0 fused kernel (used iff ws too small) ----------------
__launch_bounds__(256, 2)
__global__ void halo_attn(const float* __restrict__ x,
                          const float* __restrict__ qkv_w,
                          const float* __restrict__ relh_g,
                          const float* __restrict__ relw_g,
                          float* __restrict__ out)
{
    const int blk  = blockIdx.x;
    const int head = blk & 3;
    const int j    = (blk >> 2) & 15;
    const int i    = (blk >> 6) & 15;
    const int b    = blk >> 10;
    const int tid = threadIdx.x;
    const int wv  = tid >> 6;
    const int ln  = tid & 63;
    const int lr  = ln & 15;
    const int lg  = ln >> 4;

    __shared__ __align__(16) union { short xs[112*128]; short pbuf[64*224]; } XP;
    __shared__ __align__(16) short kbuf[208*32];
    __shared__ __align__(16) short vbufT[32*224];
    __shared__ __align__(16) short qbuf[64*32];
    __shared__ float smax[4*64];
    __shared__ float ssum[4*64];
    __shared__ float relh[224];
    __shared__ float relw[224];

    for (int t = tid; t < 32*224/2; t += 256) ((int*)vbufT)[t] = 0;
    for (int t = tid; t < 224; t += 256) { relh[t] = relh_g[t]; relw[t] = relw_g[t]; }

    bf16x8 Bw[6][4];
    #pragma unroll
    for (int n = 0; n < 6; ++n) {
        const int obase = (n < 2) ? head*32 + n*16
                        : (n < 4) ? 128 + head*32 + (n-2)*16
                                  : 256 + head*32 + (n-4)*16;
        const float* wp0 = qkv_w + (obase + lr)*128;
        #pragma unroll
        for (int ks = 0; ks < 4; ++ks) {
            const float* wp = wp0 + ks*32 + lg*8;
            bf16x8 f;
            #pragma unroll
            for (int e = 0; e < 8; ++e) f[e] = f2bf(wp[e]);
            Bw[n][ks] = f;
        }
    }

    for (int ph = 0; ph < 2; ++ph) {
        __syncthreads();
        for (int t = tid; t < 112*128; t += 256) {
            const int ch = t / 112;
            const int p  = t - ch*112;
            float val = 0.f;
            if (p < 98) {
                const int P  = ph*98 + p;
                const int wr = P / 14, wc = P - wr*14;
                const int gr = i*8 - 3 + wr, gc = j*8 - 3 + wc;
                if ((unsigned)gr < 128u && (unsigned)gc < 128u)
                    val = x[((b*128 + ch)*128 + gr)*128 + gc];
            }
            XP.xs[p*128 + (ch & 7) + 8*((ch >> 3) ^ (p & 15))] = f2bf(val);
        }
        __syncthreads();

        for (int mt = wv; mt < 7; mt += 4) {
            const int row = mt*16 + lr;
            bf16x8 A[4];
            #pragma unroll
            for (int ks = 0; ks < 4; ++ks)
                A[ks] = *(const bf16x8*)&XP.xs[row*128 + 8*((ks*4 + lg) ^ (row & 15))];
            #pragma unroll
            for (int n = 0; n < 6; ++n) {
                f32x4 acc = {0.f, 0.f, 0.f, 0.f};
                #pragma unroll
                for (int ks = 0; ks < 4; ++ks)
                    acc = __builtin_amdgcn_mfma_f32_16x16x32_bf16(A[ks], Bw[n][ks], acc, 0, 0, 0);
                #pragma unroll
                for (int r = 0; r < 4; ++r) {
                    const int p = mt*16 + lg*4 + r;
                    if (p >= 98) continue;
                    const int P  = ph*98 + p;
                    const int wr = P / 14, wc = P - wr*14;
                    const float val = acc[r];
                    if (n < 2) {
                        if (wr >= 3 && wr <= 10 && wc >= 3 && wc <= 10) {
                            const int qi = (wr-3)*8 + (wc-3);
                            const int dd = n*16 + lr;
                            qbuf[qi*32 + (dd & 7) + 8*((dd >> 3) ^ ((qi >> 1) & 3))] =
                                f2bf(val * 0.17677669529663687f);
                        }
                    } else if (n < 4) {
                        const int dd = (n-2)*16 + lr;
                        const float bias = (dd < 16) ? relh[wr*16 + dd] : relw[wc*16 + dd - 16];
                        kbuf[P*32 + (dd & 7) + 8*((dd >> 3) ^ ((P >> 1) & 3))] = f2bf(val + bias);
                    } else {
                        const int dd = (n-4)*16 + lr;
                        vbufT[dd*224 + (P & 7) + 8*((P >> 3) ^ ((dd >> 1) & 3))] = f2bf(val);
                    }
                }
            }
        }
    }
    __syncthreads();

    bf16x8 Aq[4];
    #pragma unroll
    for (int mt = 0; mt < 4; ++mt) {
        const int row = mt*16 + lr;
        Aq[mt] = *(const bf16x8*)&qbuf[row*32 + 8*(lg ^ ((row >> 1) & 3))];
    }

    f32x4 sim[4][4];
    #pragma unroll
    for (int ntl = 0; ntl < 4; ++ntl) {
        const int nt = wv + ntl*4;
        if (nt > 12) continue;
        const int P = nt*16 + lr;
        const bf16x8 Bk = *(const bf16x8*)&kbuf[P*32 + 8*(lg ^ ((P >> 1) & 3))];
        #pragma unroll
        for (int mt = 0; mt < 4; ++mt) {
            const f32x4 z = {0.f, 0.f, 0.f, 0.f};
            sim[ntl][mt] = __builtin_amdgcn_mfma_f32_16x16x32_bf16(Aq[mt], Bk, z, 0, 0, 0);
        }
    }

    for (int t = tid; t < 64*224/2; t += 256) ((int*)XP.pbuf)[t] = 0;

    #pragma unroll
    for (int mt = 0; mt < 4; ++mt)
    #pragma unroll
    for (int r = 0; r < 4; ++r) {
        float m = -1e30f;
        #pragma unroll
        for (int ntl = 0; ntl < 4; ++ntl) {
            const int nt = wv + ntl*4;
            if (nt > 12) continue;
            const int key = nt*16 + lr;
            if (key < 196) m = fmaxf(m, sim[ntl][mt][r]);
        }
        #pragma unroll
        for (int off = 1; off < 16; off <<= 1)
            m = fmaxf(m, __shfl_xor(m, off, 64));
        if (lr == 0) smax[wv*64 + mt*16 + lg*4 + r] = m;
    }
    __syncthreads();

    #pragma unroll
    for (int mt = 0; mt < 4; ++mt)
    #pragma unroll
    for (int r = 0; r < 4; ++r) {
        const int qrow = mt*16 + lg*4 + r;
        const float gm = fmaxf(fmaxf(smax[qrow], smax[64+qrow]),
                               fmaxf(smax[128+qrow], smax[192+qrow]));
        float s = 0.f;
        #pragma unroll
        for (int ntl = 0; ntl < 4; ++ntl) {
            const int nt = wv + ntl*4;
            if (nt > 12) continue;
            const int key = nt*16 + lr;
            float e = (key < 196) ? __expf(sim[ntl][mt][r] - gm) : 0.f;
            sim[ntl][mt][r] = e;
            s += e;
        }
        #pragma unroll
        for (int off = 1; off < 16; off <<= 1)
            s += __shfl_xor(s, off, 64);
        if (lr == 0) ssum[wv*64 + qrow] = s;
    }
    __syncthreads();

    #pragma unroll
    for (int mt = 0; mt < 4; ++mt)
    #pragma unroll
    for (int r = 0; r < 4; ++r) {
        const int qrow = mt*16 + lg*4 + r;
        const float rinv = 1.f / (ssum[qrow] + ssum[64+qrow] + ssum[128+qrow] + ssum[192+qrow]);
        #pragma unroll
        for (int ntl = 0; ntl < 4; ++ntl) {
            const int nt = wv + ntl*4;
            if (nt > 12) continue;
            const int key = nt*16 + lr;
            XP.pbuf[qrow*224 + (key & 7) + 8*((key >> 3) ^ ((qrow >> 1) & 3))] =
                f2bf(sim[ntl][mt][r] * rinv);
        }
    }
    __syncthreads();

    f32x4 oacc[2] = {{0.f,0.f,0.f,0.f},{0.f,0.f,0.f,0.f}};
    const int mt = wv;
    #pragma unroll
    for (int ks = 0; ks < 7; ++ks) {
        const int row = mt*16 + lr;
        const int g = ks*4 + lg;
        const bf16x8 Ap = *(const bf16x8*)&XP.pbuf[row*224 + 8*(g ^ ((row >> 1) & 3))];
        #pragma unroll
        for (int n = 0; n < 2; ++n) {
            const int dd = n*16 + lr;
            const bf16x8 Bv = *(const bf16x8*)&vbufT[dd*224 + 8*(g ^ ((dd >> 1) & 3))];
            oacc[n] = __builtin_amdgcn_mfma_f32_16x16x32_bf16(Ap, Bv, oacc[n], 0, 0, 0);
        }
    }

    #pragma unroll
    for (int n = 0; n < 2; ++n) {
        const int dd = n*16 + lr;
        const int c  = head*32 + dd;
        const int qb = mt*16 + lg*4;
        const int rb = qb >> 3, cb = qb & 7;
        float* op = out + ((b*128 + c)*128 + (i*8 + rb))*128 + j*8 + cb;
        *(f32x4*)op = oacc[n];
    }
}

extern "C" void kernel_launch(void* const* d_in, const int* in_sizes, int n_in,
                              void* d_out, int out_size, void* d_ws, size_t ws_size,
                              hipStream_t stream)
{
    const float* x  = (const float*)d_in[0];
    const float* w  = (const float*)d_in[1];
    const float* rh = (const float*)d_in[2];
    const float* rw = (const float*)d_in[3];
    float* o = (float*)d_out;

    const size_t Q_ELEMS = (size_t)8192 * 2048;             // 16,777,216
    const size_t K_ELEMS = (size_t)32 * 16384 * 32;         // 16,777,216
    const size_t V_ELEMS = (size_t)32 * 128 * 32 * 32 * 4;  // 16,777,216
    const size_t NEED = (Q_ELEMS + K_ELEMS + V_ELEMS) * 2 + 1024;

    if (ws_size >= NEED) {
        short* ws_q = (short*)d_ws;
        short* ws_k = ws_q + Q_ELEMS;
        short* ws_v = ws_k + K_ELEMS;
        qkv_gemm<<<dim3(512), dim3(256), 0, stream>>>(x, w, ws_q, ws_k, ws_v);
        attn4<<<dim3(4096), dim3(256), 0, stream>>>(ws_q, ws_k, ws_v, rh, rw, o);
    } else {
        halo_attn<<<dim3(8192), dim3(256), 0, stream>>>(x, w, rh, rw, o);
    }
}

// Round 23
// 104.397 us; speedup vs baseline: 1.1322x; 1.1322x over previous
//
#include <hip/hip_runtime.h>
#include <hip/hip_bf16.h>

// HaloNet block attention. B=8, C=128, H=W=128, HEADS=4, D=32, BLOCK=8, HALO=3,
// WIN=14, slots padded to 14x16=224.
//
// FINAL = R15/R20 optimum (104.7 us, confirmed twice; 10.6x over baseline).
// Complete falsification ledger: R16 qhv hoist (-occupancy), R17/R18 ot-split
// (2x x traffic), R19 pixel-split (halved load amortization), R21 wcvt fold
// (+34 us: VGPR 56->80 + convert chain on critical path), R8/R9 forced
// prefetch (allocator/asm hazards), R12 locality swizzle (null).
//
// 3-kernel pipeline through d_ws:
//   ws_q : bf16 [b][i][j][head][64 qrow][32 d]           (block-gathered, prescaled)
//   ws_k : bf16 [b*4+head][16384 pix][32 d]              (head-major pixel-major)
//   ws_v : bf16 [b*4+head][row 128][colquad 32][d 32][4] (quad-interleaved v)
//   ws_w : bf16 [384][128]  (q rows prescaled by d^-0.5 * 1/ln2)
// Fallback (ws too small): round-0 fused kernel.

typedef __attribute__((ext_vector_type(8))) short bf16x8;
typedef __attribute__((ext_vector_type(4))) short bf16x4;
typedef __attribute__((ext_vector_type(4))) float f32x4;
union BF8 { bf16x8 v; unsigned u[4]; };
union BF4 { bf16x4 v; unsigned u[2]; };

#define DEVI static __device__ __forceinline__

DEVI short f2bf(float f) {
    __bf16 h = (__bf16)f;                      // fptrunc (RNE)
    union { __bf16 h; short s; } c; c.h = h; return c.s;
}
DEVI unsigned pk2(float a, float b) {
    return (unsigned)(unsigned short)f2bf(a) | ((unsigned)(unsigned short)f2bf(b) << 16);
}

#if defined(__has_builtin)
#  if __has_builtin(__builtin_amdgcn_exp2f)
#    define EXP2(x) __builtin_amdgcn_exp2f(x)
#  else
#    define EXP2(x) exp2f(x)
#  endif
#else
#  define EXP2(x) exp2f(x)
#endif

#if defined(__has_builtin)
#  if __has_builtin(__builtin_amdgcn_mfma_f32_16x16x16bf16_1k)
#    define HAVE_MFMA16_1K 1
#  endif
#endif

DEVI f32x4 mfma16(bf16x4 a, bf16x4 b, f32x4 c) {
#ifdef HAVE_MFMA16_1K
    return __builtin_amdgcn_mfma_f32_16x16x16bf16_1k(a, b, c, 0, 0, 0);
#else
    f32x4 d;
    asm("v_mfma_f32_16x16x16_bf16 %0, %1, %2, %3" : "=v"(d) : "v"(a), "v"(b), "v"(c));
    return d;
#endif
}

// q prescale: d^-0.5 * 1/ln2  (sim computed in log2 units; exp2 in softmax)
#define QSCALE (0.17677669529663687f * 1.4426950408889634f)

// ---------------- kernel 0: weight convert (+ q prescale) ----------------
__global__ void wcvt(const float* __restrict__ w, short* __restrict__ ws_w) {
    int e = blockIdx.x * 256 + threadIdx.x;
    if (e < 384 * 128) {
        float v = w[e];
        if (e < 128 * 128) v *= QSCALE;
        ws_w[e] = f2bf(v);
    }
}

// ---------------- kernel 1: QKV GEMM (M=384 o, N=131072 pix, K=128) ----------------
__launch_bounds__(256)
__global__ void qkv_gemm(const float* __restrict__ x, const short* __restrict__ ws_w,
                         short* __restrict__ ws_q, short* __restrict__ ws_k,
                         short* __restrict__ ws_v) {
    const int blk = blockIdx.x;
    const int b = blk >> 6;
    const int pixbase = (blk & 63) << 8;
    const int tid = threadIdx.x, wv = tid >> 6, ln = tid & 63;
    const int lr = ln & 15, lg = ln >> 4;
    const int n0 = pixbase + wv * 64;
    const f32x4 zz = {0.f, 0.f, 0.f, 0.f};

    // B-frags: X[c][pix]; lane lr = pix col, lg*8+e = channel. As an A-frag the
    // same registers represent X^T[pix][c] (identical lane->element indexing).
    BF8 Bx[4][4];
    #pragma unroll
    for (int nt = 0; nt < 4; ++nt) {
        const int pix = n0 + nt * 16 + lr;
        #pragma unroll
        for (int ks = 0; ks < 4; ++ks) {
            const float* xp = x + (((size_t)((b << 7) + ks * 32 + lg * 8)) << 14) + pix;
            float f[8];
            #pragma unroll
            for (int e = 0; e < 8; ++e) f[e] = xp[(size_t)e << 14];
            Bx[nt][ks].u[0] = pk2(f[0], f[1]); Bx[nt][ks].u[1] = pk2(f[2], f[3]);
            Bx[nt][ks].u[2] = pk2(f[4], f[5]); Bx[nt][ks].u[3] = pk2(f[6], f[7]);
        }
    }

    for (int ot = 0; ot < 24; ++ot) {
        bf16x8 Aw[4];
        #pragma unroll
        for (int ks = 0; ks < 4; ++ks)
            Aw[ks] = *(const bf16x8*)&ws_w[(ot * 16 + lr) * 128 + ks * 32 + lg * 8];

        if (ot < 16) {                       // q/k: C[o][pix], 8B packed stores
            f32x4 acc[4];
            #pragma unroll
            for (int nt = 0; nt < 4; ++nt) {
                acc[nt] = zz;
                #pragma unroll
                for (int ks = 0; ks < 4; ++ks)
                    acc[nt] = __builtin_amdgcn_mfma_f32_16x16x32_bf16(Aw[ks], Bx[nt][ks].v, acc[nt], 0, 0, 0);
            }
            if (ot < 8) {                    // q -> block-gathered [blkhead][qrow][32]
                const int head = ot >> 1, dd0 = ((ot & 1) << 4) + lg * 4;
                #pragma unroll
                for (int nt = 0; nt < 4; ++nt) {
                    const int pix = n0 + nt * 16 + lr;
                    const int gr = pix >> 7, gc = pix & 127;
                    const int ii = gr >> 3, jj = gc >> 3;
                    const int qrow = ((gr & 7) << 3) | (gc & 7);
                    size_t off = ((size_t)((((b * 16 + ii) * 16 + jj) << 2) + head) << 11) + qrow * 32 + dd0;
                    *(uint2*)&ws_q[off] = make_uint2(pk2(acc[nt][0], acc[nt][1]), pk2(acc[nt][2], acc[nt][3]));
                }
            } else {                         // k -> [bh][pix][32]
                const int head = (ot - 8) >> 1, dd0 = (((ot - 8) & 1) << 4) + lg * 4;
                const size_t kb = ((size_t)(b * 4 + head)) << 19;
                #pragma unroll
                for (int nt = 0; nt < 4; ++nt) {
                    const int pix = n0 + nt * 16 + lr;
                    *(uint2*)&ws_k[kb + pix * 32 + dd0] =
                        make_uint2(pk2(acc[nt][0], acc[nt][1]), pk2(acc[nt][2], acc[nt][3]));
                }
            }
        } else {                             // v: SWAPPED mfma -> C[pix][o] (proven R8)
            const int vch = ((ot - 16) << 4) + lr;     // o - 256 for this lane
            const int headv = vch >> 5, dv = vch & 31;
            f32x4 accT[4];
            #pragma unroll
            for (int nt = 0; nt < 4; ++nt) {
                accT[nt] = zz;
                #pragma unroll
                for (int ks = 0; ks < 4; ++ks)
                    accT[nt] = __builtin_amdgcn_mfma_f32_16x16x32_bf16(Bx[nt][ks].v, Aw[ks], accT[nt], 0, 0, 0);
            }
            #pragma unroll
            for (int nt = 0; nt < 4; ++nt) {
                const int pixq = n0 + nt * 16 + lg * 4;   // 4-aligned, quad in one row
                const int gr = pixq >> 7, gcq = (pixq & 127) >> 2;
                const size_t idx = ((((size_t)(b * 4 + headv) * 128 + gr) * 32 + gcq) * 32 + dv) * 4;
                *(uint2*)&ws_v[idx] =
                    make_uint2(pk2(accT[nt][0], accT[nt][1]), pk2(accT[nt][2], accT[nt][3]));
            }
        }
    }
}

// ---------------- kernel 2: attention; block=(b,i,j,half), wave=head, 32 qrows ----------------
template<bool EDGE>
DEVI void attn_body(int b, int i, int j, int head, int ln, int mt0,
                    const short* __restrict__ ws_q, const short* __restrict__ ws_k,
                    const short* __restrict__ ws_v,
                    const float* __restrict__ rel_h, const float* __restrict__ rel_w,
                    float* __restrict__ out) {
    const int lr = ln & 15, lg = ln >> 4;
    const f32x4 zz = {0.f, 0.f, 0.f, 0.f};
    const int bh = b * 4 + head;

    const short* qbase = ws_q + ((size_t)((((b * 16 + i) * 16 + j) << 2) + head) << 11);
    const short* kbase = ws_k + (((size_t)bh) << 19);
    const short* vbase = ws_v + (((size_t)bh) << 19);   // 128*32*32*4 = 2^19

    // q B-frags for this wave's 2 m-tiles (n = qrow = (mt0+m)*16+lr, k = d = lg*8+e)
    bf16x8 Bq[2];
    #pragma unroll
    for (int m = 0; m < 2; ++m)
        Bq[m] = *(const bf16x8*)&qbase[((mt0 + m) * 16 + lr) * 32 + lg * 8];

    // rel-pos A-frags: Ah = rel_h (m-row = wr, d 0..15), Aw (m-row = wc, d 16..31)
    BF8 Ah, Awf;
    #pragma unroll
    for (int wd = 0; wd < 4; ++wd) { Ah.u[wd] = 0u; Awf.u[wd] = 0u; }
    if (lr < 14) {
        if (lg < 2) {
            const float* rp = rel_h + lr * 16 + lg * 8;
            #pragma unroll
            for (int wd = 0; wd < 4; ++wd) Ah.u[wd] = pk2(rp[2 * wd], rp[2 * wd + 1]);
        } else {
            const float* rp = rel_w + lr * 16 + (lg - 2) * 8;
            #pragma unroll
            for (int wd = 0; wd < 4; ++wd) Awf.u[wd] = pk2(rp[2 * wd], rp[2 * wd + 1]);
        }
    }
    // qh4[m][r] = qh(qrow, wr=lg*4+r); qw4[m][r] = qw(qrow, wc=lg*4+r)
    f32x4 qh4[2], qw4[2];
    #pragma unroll
    for (int m = 0; m < 2; ++m) {
        qh4[m] = __builtin_amdgcn_mfma_f32_16x16x32_bf16(Ah.v, Bq[m], zz, 0, 0, 0);
        qw4[m] = __builtin_amdgcn_mfma_f32_16x16x32_bf16(Awf.v, Bq[m], zz, 0, 0, 0);
    }
    if (lg == 3) {     // phantom slots wc=14,15: bias -> -16384 so exp2 -> exact 0
        #pragma unroll
        for (int m = 0; m < 2; ++m) { qw4[m][2] = -16384.f; qw4[m][3] = -16384.f; }
    }

    BF4 Bones; Bones.u[0] = 0x3F803F80u; Bones.u[1] = 0x3F803F80u;

    // t-invariant edge precompute
    const int gc   = j * 8 - 3 + lr;                       // K column for this lane
    const int gcc  = EDGE ? min(max(gc, 0), 127) : gc;
    const bool gcBad = EDGE && (gc != gcc);
    // V: lane needs window cols gc0..gc0+3, gc0 = j*8-3+lg*4 (== 1 mod 4):
    // quad A = 2j+lg-1 supplies cols {1,2,3}; quad B = A+1 supplies col {0}.
    const int qAraw = 2 * j + lg - 1;
    const int qA = EDGE ? min(max(qAraw, 0), 31) : qAraw;
    const int qB = EDGE ? min(qAraw + 1, 31) : (qAraw + 1);
    const int oA0 = (qA * 32 + lr) * 4;        // quad A, d = lr
    const int oA1 = oA0 + 64;                  // quad A, d = 16+lr
    const int oB0 = (qB * 32 + lr) * 4;
    const int oB1 = oB0 + 64;
    unsigned mmc0 = 0xFFFFFFFFu, mmc1 = 0xFFFFFFFFu;
    if (EDGE) {
        const int gc0 = j * 8 - 3 + lg * 4;
        const int lo = max(0, -gc0), hi = min(3, 127 - gc0);
        const unsigned bits = (lo <= hi) ? (((0xFu >> (3 - (hi - lo))) << lo) & 0xFu) : 0u;
        mmc0 = ((bits & 1u) ? 0x0000FFFFu : 0u) | ((bits & 2u) ? 0xFFFF0000u : 0u);
        mmc1 = ((bits & 4u) ? 0x0000FFFFu : 0u) | ((bits & 8u) ? 0xFFFF0000u : 0u);
    }

    // two independent accumulator sets: stream A (t=0..6), stream B (t=7..13)
    f32x4 a0A[2] = {zz, zz}, a1A[2] = {zz, zz}, sAA[2] = {zz, zz};
    f32x4 a0B[2] = {zz, zz}, a1B[2] = {zz, zz}, sAB[2] = {zz, zz};

#define STEP(T, A0, A1, SA) { \
        const int gr_ = i * 8 - 3 + (T); \
        const bool grOK_ = !EDGE || ((unsigned)gr_ < 128u); \
        const int grc_ = EDGE ? min(max(gr_, 0), 127) : gr_; \
        BF8 Ak_; \
        Ak_.v = *(const bf16x8*)&kbase[((grc_ << 7) + gcc) * 32 + lg * 8]; \
        if (EDGE && (gcBad || !grOK_)) { Ak_.u[0] = 0; Ak_.u[1] = 0; Ak_.u[2] = 0; Ak_.u[3] = 0; } \
        const int vrow_ = grc_ << 12; \
        const uint2 aA0_ = *(const uint2*)&vbase[vrow_ + oA0]; \
        const uint2 aA1_ = *(const uint2*)&vbase[vrow_ + oA1]; \
        const unsigned bB0_ = *(const unsigned short*)&vbase[vrow_ + oB0]; \
        const unsigned bB1_ = *(const unsigned short*)&vbase[vrow_ + oB1]; \
        BF4 Bv0_, Bv1_; \
        Bv0_.u[0] = __builtin_amdgcn_alignbit(aA0_.y, aA0_.x, 16); \
        Bv0_.u[1] = __builtin_amdgcn_alignbit(bB0_, aA0_.y, 16); \
        Bv1_.u[0] = __builtin_amdgcn_alignbit(aA1_.y, aA1_.x, 16); \
        Bv1_.u[1] = __builtin_amdgcn_alignbit(bB1_, aA1_.y, 16); \
        if (EDGE) { \
            const unsigned mm0_ = grOK_ ? mmc0 : 0u; \
            const unsigned mm1_ = grOK_ ? mmc1 : 0u; \
            Bv0_.u[0] &= mm0_; Bv0_.u[1] &= mm1_; Bv1_.u[0] &= mm0_; Bv1_.u[1] &= mm1_; \
        } \
        _Pragma("unroll") \
        for (int m = 0; m < 2; ++m) { \
            const float qh_ = __shfl(qh4[m][(T) & 3], (((T) >> 2) << 4) | lr, 64); \
            f32x4 cin_; \
            _Pragma("unroll") \
            for (int r = 0; r < 4; ++r) cin_[r] = qw4[m][r] + qh_; \
            const f32x4 p_ = __builtin_amdgcn_mfma_f32_16x16x32_bf16(Ak_.v, Bq[m], cin_, 0, 0, 0); \
            BF4 Ap_; \
            Ap_.u[0] = pk2(EXP2(p_[0]), EXP2(p_[1])); \
            Ap_.u[1] = pk2(EXP2(p_[2]), EXP2(p_[3])); \
            A0[m] = mfma16(Ap_.v, Bv0_.v, A0[m]); \
            A1[m] = mfma16(Ap_.v, Bv1_.v, A1[m]); \
            SA[m] = mfma16(Ap_.v, Bones.v, SA[m]); \
        } \
    }

    #pragma unroll
    for (int t = 0; t < 7; ++t) {
        STEP(t,     a0A, a1A, sAA)
        STEP(t + 7, a0B, a1B, sAB)
    }
#undef STEP

    // epilogue: merge streams; s for qrow = (mt0+m)*16+lg*4+r is in reg r of this lane
    #pragma unroll
    for (int m = 0; m < 2; ++m) {
        f32x4 acc0, acc1;
        #pragma unroll
        for (int r = 0; r < 4; ++r) {
            const float rinv = __builtin_amdgcn_rcpf(sAA[m][r] + sAB[m][r]);
            acc0[r] = (a0A[m][r] + a0B[m][r]) * rinv;
            acc1[r] = (a1A[m][r] + a1B[m][r]) * rinv;
        }
        const int qb = (mt0 + m) * 16 + lg * 4;
        float* op = out + (((size_t)(b * 128 + head * 32)) << 14)
                        + ((i * 8 + (qb >> 3)) << 7) + j * 8 + (qb & 7);
        *(f32x4*)(op + ((size_t)lr << 14)) = acc0;
        *(f32x4*)(op + ((size_t)(16 + lr) << 14)) = acc1;
    }
}

__launch_bounds__(256, 2)
__global__ void attn4(const short* __restrict__ ws_q, const short* __restrict__ ws_k,
                      const short* __restrict__ ws_v,
                      const float* __restrict__ rel_h, const float* __restrict__ rel_w,
                      float* __restrict__ out) {
    // L2-capacity-aware XCD swizzle (R12; ~neutral vs R11 but passing/kept).
    const int bid = blockIdx.x;
    const int x = bid & 7, n = bid >> 3;
    const int g = x + ((n >> 7) << 3);
    const int l = n & 127;
    const int b = g >> 2;
    const int i = ((g & 3) << 2) | (l >> 5);
    const int j = (l >> 1) & 15;
    const int half = l & 1;
    const int head = threadIdx.x >> 6, ln = threadIdx.x & 63;
    if (i == 0 || i == 15 || j == 0 || j == 15)
        attn_body<true>(b, i, j, head, ln, half * 2, ws_q, ws_k, ws_v, rel_h, rel_w, out);
    else
        attn_body<false>(b, i, j, head, ln, half * 2, ws_q, ws_k, ws_v, rel_h, rel_w, out);
}

// ---------------- fallback: round-0 fused kernel (used iff ws too small) ----------------
__launch_bounds__(256, 2)
__global__ void halo_attn(const float* __restrict__ x,
                          const float* __restrict__ qkv_w,
                          const float* __restrict__ relh_g,
                          const float* __restrict__ relw_g,
                          float* __restrict__ out)
{
    const int blk  = blockIdx.x;
    const int head = blk & 3;
    const int j    = (blk >> 2) & 15;
    const int i    = (blk >> 6) & 15;
    const int b    = blk >> 10;
    const int tid = threadIdx.x;
    const int wv  = tid >> 6;
    const int ln  = tid & 63;
    const int lr  = ln & 15;
    const int lg  = ln >> 4;

    __shared__ __align__(16) union { short xs[112*128]; short pbuf[64*224]; } XP;
    __shared__ __align__(16) short kbuf[208*32];
    __shared__ __align__(16) short vbufT[32*224];
    __shared__ __align__(16) short qbuf[64*32];
    __shared__ float smax[4*64];
    __shared__ float ssum[4*64];
    __shared__ float relh[224];
    __shared__ float relw[224];

    for (int t = tid; t < 32*224/2; t += 256) ((int*)vbufT)[t] = 0;
    for (int t = tid; t < 224; t += 256) { relh[t] = relh_g[t]; relw[t] = relw_g[t]; }

    bf16x8 Bw[6][4];
    #pragma unroll
    for (int n = 0; n < 6; ++n) {
        const int obase = (n < 2) ? head*32 + n*16
                        : (n < 4) ? 128 + head*32 + (n-2)*16
                                  : 256 + head*32 + (n-4)*16;
        const float* wp0 = qkv_w + (obase + lr)*128;
        #pragma unroll
        for (int ks = 0; ks < 4; ++ks) {
            const float* wp = wp0 + ks*32 + lg*8;
            bf16x8 f;
            #pragma unroll
            for (int e = 0; e < 8; ++e) f[e] = f2bf(wp[e]);
            Bw[n][ks] = f;
        }
    }

    for (int ph = 0; ph < 2; ++ph) {
        __syncthreads();
        for (int t = tid; t < 112*128; t += 256) {
            const int ch = t / 112;
            const int p  = t - ch*112;
            float val = 0.f;
            if (p < 98) {
                const int P  = ph*98 + p;
                const int wr = P / 14, wc = P - wr*14;
                const int gr = i*8 - 3 + wr, gc = j*8 - 3 + wc;
                if ((unsigned)gr < 128u && (unsigned)gc < 128u)
                    val = x[((b*128 + ch)*128 + gr)*128 + gc];
            }
            XP.xs[p*128 + (ch & 7) + 8*((ch >> 3) ^ (p & 15))] = f2bf(val);
        }
        __syncthreads();

        for (int mt = wv; mt < 7; mt += 4) {
            const int row = mt*16 + lr;
            bf16x8 A[4];
            #pragma unroll
            for (int ks = 0; ks < 4; ++ks)
                A[ks] = *(const bf16x8*)&XP.xs[row*128 + 8*((ks*4 + lg) ^ (row & 15))];
            #pragma unroll
            for (int n = 0; n < 6; ++n) {
                f32x4 acc = {0.f, 0.f, 0.f, 0.f};
                #pragma unroll
                for (int ks = 0; ks < 4; ++ks)
                    acc = __builtin_amdgcn_mfma_f32_16x16x32_bf16(A[ks], Bw[n][ks], acc, 0, 0, 0);
                #pragma unroll
                for (int r = 0; r < 4; ++r) {
                    const int p = mt*16 + lg*4 + r;
                    if (p >= 98) continue;
                    const int P  = ph*98 + p;
                    const int wr = P / 14, wc = P - wr*14;
                    const float val = acc[r];
                    if (n < 2) {
                        if (wr >= 3 && wr <= 10 && wc >= 3 && wc <= 10) {
                            const int qi = (wr-3)*8 + (wc-3);
                            const int dd = n*16 + lr;
                            qbuf[qi*32 + (dd & 7) + 8*((dd >> 3) ^ ((qi >> 1) & 3))] =
                                f2bf(val * 0.17677669529663687f);
                        }
                    } else if (n < 4) {
                        const int dd = (n-2)*16 + lr;
                        const float bias = (dd < 16) ? relh[wr*16 + dd] : relw[wc*16 + dd - 16];
                        kbuf[P*32 + (dd & 7) + 8*((dd >> 3) ^ ((P >> 1) & 3))] = f2bf(val + bias);
                    } else {
                        const int dd = (n-4)*16 + lr;
                        vbufT[dd*224 + (P & 7) + 8*((P >> 3) ^ ((dd >> 1) & 3))] = f2bf(val);
                    }
                }
            }
        }
    }
    __syncthreads();

    bf16x8 Aq[4];
    #pragma unroll
    for (int mt = 0; mt < 4; ++mt) {
        const int row = mt*16 + lr;
        Aq[mt] = *(const bf16x8*)&qbuf[row*32 + 8*(lg ^ ((row >> 1) & 3))];
    }

    f32x4 sim[4][4];
    #pragma unroll
    for (int ntl = 0; ntl < 4; ++ntl) {
        const int nt = wv + ntl*4;
        if (nt > 12) continue;
        const int P = nt*16 + lr;
        const bf16x8 Bk = *(const bf16x8*)&kbuf[P*32 + 8*(lg ^ ((P >> 1) & 3))];
        #pragma unroll
        for (int mt = 0; mt < 4; ++mt) {
            const f32x4 z = {0.f, 0.f, 0.f, 0.f};
            sim[ntl][mt] = __builtin_amdgcn_mfma_f32_16x16x32_bf16(Aq[mt], Bk, z, 0, 0, 0);
        }
    }

    for (int t = tid; t < 64*224/2; t += 256) ((int*)XP.pbuf)[t] = 0;

    #pragma unroll
    for (int mt = 0; mt < 4; ++mt)
    #pragma unroll
    for (int r = 0; r < 4; ++r) {
        float m = -1e30f;
        #pragma unroll
        for (int ntl = 0; ntl < 4; ++ntl) {
            const int nt = wv + ntl*4;
            if (nt > 12) continue;
            const int key = nt*16 + lr;
            if (key < 196) m = fmaxf(m, sim[ntl][mt][r]);
        }
        #pragma unroll
        for (int off = 1; off < 16; off <<= 1)
            m = fmaxf(m, __shfl_xor(m, off, 64));
        if (lr == 0) smax[wv*64 + mt*16 + lg*4 + r] = m;
    }
    __syncthreads();

    #pragma unroll
    for (int mt = 0; mt < 4; ++mt)
    #pragma unroll
    for (int r = 0; r < 4; ++r) {
        const int qrow = mt*16 + lg*4 + r;
        const float gm = fmaxf(fmaxf(smax[qrow], smax[64+qrow]),
                               fmaxf(smax[128+qrow], smax[192+qrow]));
        float s = 0.f;
        #pragma unroll
        for (int ntl = 0; ntl < 4; ++ntl) {
            const int nt = wv + ntl*4;
            if (nt > 12) continue;
            const int key = nt*16 + lr;
            float e = (key < 196) ? __expf(sim[ntl][mt][r] - gm) : 0.f;
            sim[ntl][mt][r] = e;
            s += e;
        }
        #pragma unroll
        for (int off = 1; off < 16; off <<= 1)
            s += __shfl_xor(s, off, 64);
        if (lr == 0) ssum[wv*64 + qrow] = s;
    }
    __syncthreads();

    #pragma unroll
    for (int mt = 0; mt < 4; ++mt)
    #pragma unroll
    for (int r = 0; r < 4; ++r) {
        const int qrow = mt*16 + lg*4 + r;
        const float rinv = 1.f / (ssum[qrow] + ssum[64+qrow] + ssum[128+qrow] + ssum[192+qrow]);
        #pragma unroll
        for (int ntl = 0; ntl < 4; ++ntl) {
            const int nt = wv + ntl*4;
            if (nt > 12) continue;
            const int key = nt*16 + lr;
            XP.pbuf[qrow*224 + (key & 7) + 8*((key >> 3) ^ ((qrow >> 1) & 3))] =
                f2bf(sim[ntl][mt][r] * rinv);
        }
    }
    __syncthreads();

    f32x4 oacc[2] = {{0.f,0.f,0.f,0.f},{0.f,0.f,0.f,0.f}};
    const int mt = wv;
    #pragma unroll
    for (int ks = 0; ks < 7; ++ks) {
        const int row = mt*16 + lr;
        const int g = ks*4 + lg;
        const bf16x8 Ap = *(const bf16x8*)&XP.pbuf[row*224 + 8*(g ^ ((row >> 1) & 3))];
        #pragma unroll
        for (int n = 0; n < 2; ++n) {
            const int dd = n*16 + lr;
            const bf16x8 Bv = *(const bf16x8*)&vbufT[dd*224 + 8*(g ^ ((dd >> 1) & 3))];
            oacc[n] = __builtin_amdgcn_mfma_f32_16x16x32_bf16(Ap, Bv, oacc[n], 0, 0, 0);
        }
    }

    #pragma unroll
    for (int n = 0; n < 2; ++n) {
        const int dd = n*16 + lr;
        const int c  = head*32 + dd;
        const int qb = mt*16 + lg*4;
        const int rb = qb >> 3, cb = qb & 7;
        float* op = out + ((b*128 + c)*128 + (i*8 + rb))*128 + j*8 + cb;
        *(f32x4*)op = oacc[n];
    }
}

extern "C" void kernel_launch(void* const* d_in, const int* in_sizes, int n_in,
                              void* d_out, int out_size, void* d_ws, size_t ws_size,
                              hipStream_t stream)
{
    const float* x  = (const float*)d_in[0];
    const float* w  = (const float*)d_in[1];
    const float* rh = (const float*)d_in[2];
    const float* rw = (const float*)d_in[3];
    float* o = (float*)d_out;

    const size_t Q_ELEMS = (size_t)8192 * 2048;             // 16,777,216
    const size_t K_ELEMS = (size_t)32 * 16384 * 32;         // 16,777,216
    const size_t V_ELEMS = (size_t)32 * 128 * 32 * 32 * 4;  // 16,777,216
    const size_t W_ELEMS = (size_t)384 * 128;               // 49,152
    const size_t NEED = (Q_ELEMS + K_ELEMS + V_ELEMS + W_ELEMS) * 2 + 1024;

    if (ws_size >= NEED) {
        short* ws_q = (short*)d_ws;
        short* ws_k = ws_q + Q_ELEMS;
        short* ws_v = ws_k + K_ELEMS;
        short* ws_w = ws_v + V_ELEMS;
        wcvt<<<dim3(192), dim3(256), 0, stream>>>(w, ws_w);
        qkv_gemm<<<dim3(512), dim3(256), 0, stream>>>(x, ws_w, ws_q, ws_k, ws_v);
        attn4<<<dim3(4096), dim3(256), 0, stream>>>(ws_q, ws_k, ws_v, rh, rw, o);
    } else {
        halo_attn<<<dim3(8192), dim3(256), 0, stream>>>(x, w, rh, rw, o);
    }
}